// Round 9
// baseline (311.673 us; speedup 1.0000x reference)
//
#include <hip/hip_runtime.h>
#include <hip/hip_bf16.h>

// MarkowitzPortfolioOptimizer. All tensors f32.
// R9 = R8 + instruction-diet:
//  - packed f32x2 (v_pk_fma/max_f32) arithmetic in vc / Newton / momentum
//  - 16 MFMA: y quantized to bf16-hi only (Sigma keeps hi+lo planes)
//  - two-tier Newton: cheap f-only pass (tol exit, carried slope) + int-count
//    fallback (exact, active-set-stable exit)
//  - theta momentum-extrapolation across FISTA iters
//  - N_POWER 96 -> 64

#define B_ROWS 16384
#define NA 64
#define N_FISTA 200
#define N_POWER 64
#define YSTRIDE 68  // floats; 2-way write banks (free), clean b128 reads

typedef __attribute__((ext_vector_type(2))) float f32x2;
typedef __attribute__((ext_vector_type(4))) float f32x4;
typedef __attribute__((ext_vector_type(8))) short s16x8;
typedef __attribute__((ext_vector_type(4))) int i32x4;

union V4 {
  i32x4 i;
  s16x8 s;
  f32x4 f;
};

__device__ __forceinline__ unsigned fu(float x) { return __float_as_uint(x); }
__device__ __forceinline__ float uf(unsigned x) { return __uint_as_float(x); }

__device__ __forceinline__ f32x2 max2(f32x2 a, f32x2 b) {
  return __builtin_elementwise_max(a, b);
}
__device__ __forceinline__ f32x2 fma2(f32x2 a, f32x2 b, f32x2 c) {
  return __builtin_elementwise_fma(a, b, c);
}

__device__ __forceinline__ float rdlane(float v, int l) {
  return __int_as_float(__builtin_amdgcn_readlane(__float_as_int(v), l));
}

__device__ __forceinline__ float wave_sum64(float x) {
#pragma unroll
  for (int m = 32; m >= 1; m >>= 1) x += __shfl_xor(x, m, 64);
  return x;
}

__device__ __forceinline__ float matvec64(const float* sig, float y) {
  float g0 = 0.f, g1 = 0.f, g2 = 0.f, g3 = 0.f;
#pragma unroll
  for (int i = 0; i < 64; i += 4) {
    g0 = fmaf(sig[i + 0], rdlane(y, i + 0), g0);
    g1 = fmaf(sig[i + 1], rdlane(y, i + 1), g1);
    g2 = fmaf(sig[i + 2], rdlane(y, i + 2), g2);
    g3 = fmaf(sig[i + 3], rdlane(y, i + 3), g3);
  }
  return (g0 + g1) + (g2 + g3);
}

// DPP helpers — ctrl must be an immediate => template parameter.
template <int CTRL>
__device__ __forceinline__ float dppf(float v) {
  return __int_as_float(
      __builtin_amdgcn_update_dpp(0, __float_as_int(v), CTRL, 0xF, 0xF, false));
}
template <int CTRL>
__device__ __forceinline__ int dppi(int v) {
  return __builtin_amdgcn_update_dpp(0, v, CTRL, 0xF, 0xF, false);
}

// 16-lane row reductions (row_ror within each DPP row)
template <int ST>
__device__ __forceinline__ void red4(float& f0, float& f1, float& f2, float& f3) {
  f0 += dppf<0x120 + ST>(f0);
  f1 += dppf<0x120 + ST>(f1);
  f2 += dppf<0x120 + ST>(f2);
  f3 += dppf<0x120 + ST>(f3);
}
template <int ST>
__device__ __forceinline__ void red5(float& f0, float& f1, float& f2, float& f3,
                                     int& enc) {
  red4<ST>(f0, f1, f2, f3);
  enc += dppi<0x120 + ST>(enc);
}

// pack 8 f32 -> bf16-hi (truncate) A/B fragment
__device__ __forceinline__ s16x8 pack_hi(const f32x4& e0, const f32x4& e1) {
  V4 hv;
  hv.i = i32x4{(int)__builtin_amdgcn_perm(fu(e0.y), fu(e0.x), 0x07060302u),
               (int)__builtin_amdgcn_perm(fu(e0.w), fu(e0.z), 0x07060302u),
               (int)__builtin_amdgcn_perm(fu(e1.y), fu(e1.x), 0x07060302u),
               (int)__builtin_amdgcn_perm(fu(e1.w), fu(e1.z), 0x07060302u)};
  return hv.s;
}

// pack 8 f32 -> bf16 hi + lo(rne residual) fragments (for Sigma, one-time)
__device__ __forceinline__ void pack_hilo(const f32x4& e0, const f32x4& e1,
                                          s16x8& hi, s16x8& lo) {
  hi = pack_hi(e0, e1);
  unsigned a0 = fu(e0.x), a1 = fu(e0.y), a2 = fu(e0.z), a3 = fu(e0.w);
  unsigned a4 = fu(e1.x), a5 = fu(e1.y), a6 = fu(e1.z), a7 = fu(e1.w);
  unsigned l0 = fu(uf(a0) - uf(a0 & 0xFFFF0000u)) + 0x8000u;
  unsigned l1 = fu(uf(a1) - uf(a1 & 0xFFFF0000u)) + 0x8000u;
  unsigned l2 = fu(uf(a2) - uf(a2 & 0xFFFF0000u)) + 0x8000u;
  unsigned l3 = fu(uf(a3) - uf(a3 & 0xFFFF0000u)) + 0x8000u;
  unsigned l4 = fu(uf(a4) - uf(a4 & 0xFFFF0000u)) + 0x8000u;
  unsigned l5 = fu(uf(a5) - uf(a5 & 0xFFFF0000u)) + 0x8000u;
  unsigned l6 = fu(uf(a6) - uf(a6 & 0xFFFF0000u)) + 0x8000u;
  unsigned l7 = fu(uf(a7) - uf(a7 & 0xFFFF0000u)) + 0x8000u;
  V4 lv;
  lv.i = i32x4{(int)__builtin_amdgcn_perm(l1, l0, 0x07060302u),
               (int)__builtin_amdgcn_perm(l3, l2, 0x07060302u),
               (int)__builtin_amdgcn_perm(l5, l4, 0x07060302u),
               (int)__builtin_amdgcn_perm(l7, l6, 0x07060302u)};
  lo = lv.s;
}

__global__ __launch_bounds__(256, 1) void fused_kernel(
    const float* __restrict__ x,
    const float* __restrict__ W1, const float* __restrict__ b1,
    const float* __restrict__ W2, const float* __restrict__ b2,
    const float* __restrict__ W3, const float* __restrict__ b3,
    const float* __restrict__ sigma, const float* __restrict__ gamma,
    float* __restrict__ w_out, float* __restrict__ mu_out) {
  __shared__ float sW1[128 * 32];
  __shared__ float sW2[32 * 16];
  __shared__ float sW3[16 * 64];
  __shared__ float sb1[32], sb2[16], sb3[64];
  __shared__ float s_step;
  __shared__ float p_lds[64 * 64];
  __shared__ __align__(16) float y_lds[4][16 * YSTRIDE];

  const int tid = threadIdx.x;
  const int wv = tid >> 6;
  const int lane = tid & 63;
  const int r16 = lane & 15;
  const int q = lane >> 4;
  const int rowbase = blockIdx.x * 64 + wv * 16;

  // ---- stage MLP weights ----
  for (int i = tid * 4; i < 128 * 32; i += 1024) *(f32x4*)&sW1[i] = *(const f32x4*)&W1[i];
  for (int i = tid; i < 32 * 16; i += 256) sW2[i] = W2[i];
  for (int i = tid * 4; i < 16 * 64; i += 1024) *(f32x4*)&sW3[i] = *(const f32x4*)&W3[i];
  if (tid < 32) sb1[tid] = b1[tid];
  if (tid < 16) sb2[tid] = b2[tid];
  if (tid < 64) sb3[tid] = b3[tid];

  // ---- B-frags: Sigma hi/lo (wave-uniform)
  s16x8 b_hi[8], b_lo[8];
#pragma unroll
  for (int t = 0; t < 4; ++t) {
#pragma unroll
    for (int s = 0; s < 2; ++s) {
      const float* sp = sigma + (16 * t + r16) * 64 + 32 * s + 8 * q;
      pack_hilo(*(const f32x4*)sp, *(const f32x4*)(sp + 4), b_hi[t * 2 + s],
                b_lo[t * 2 + s]);
    }
  }

  __syncthreads();

  // ---- phase 0: wave3 = power iteration; wave0 = MLP ----
  if (wv == 3) {
    float sig[64];
#pragma unroll
    for (int i = 0; i < 64; ++i) sig[i] = sigma[i * 64 + lane];
    float v = 0.125f;
    for (int it = 0; it < N_POWER; ++it) {
      v = matvec64(sig, v);
      if ((it & 15) == 15) v *= rsqrtf(wave_sum64(v * v));
    }
    v *= rsqrtf(wave_sum64(v * v));
    float u = matvec64(sig, v);
    float num = wave_sum64(v * u);
    if (lane == 0) s_step = 1.0f / num;
  }
  if (tid < 64) {
    const int row = blockIdx.x * 64 + tid;
    const float gamma_f = gamma[0];
    float h1[32];
#pragma unroll
    for (int j = 0; j < 32; ++j) h1[j] = sb1[j];
    for (int k = 0; k < 128; k += 4) {
      f32x4 xk = *(const f32x4*)&x[row * 128 + k];
#pragma unroll
      for (int j = 0; j < 32; ++j) {
        h1[j] = fmaf(xk.x, sW1[(k + 0) * 32 + j], h1[j]);
        h1[j] = fmaf(xk.y, sW1[(k + 1) * 32 + j], h1[j]);
        h1[j] = fmaf(xk.z, sW1[(k + 2) * 32 + j], h1[j]);
        h1[j] = fmaf(xk.w, sW1[(k + 3) * 32 + j], h1[j]);
      }
    }
#pragma unroll
    for (int j = 0; j < 32; ++j) h1[j] = fmaxf(h1[j], 0.0f);
    float h2[16];
#pragma unroll
    for (int j = 0; j < 16; ++j) h2[j] = sb2[j];
#pragma unroll
    for (int k = 0; k < 32; ++k) {
#pragma unroll
      for (int j = 0; j < 16; ++j) h2[j] = fmaf(h1[k], sW2[k * 16 + j], h2[j]);
    }
#pragma unroll
    for (int j = 0; j < 16; ++j) h2[j] = fmaxf(h2[j], 0.0f);
    for (int b = 0; b < 16; ++b) {
      f32x4 mu4;
#pragma unroll
      for (int j = 0; j < 4; ++j) {
        int o = 4 * b + j;
        float mu = sb3[o];
#pragma unroll
        for (int k = 0; k < 16; ++k) mu = fmaf(h2[k], sW3[k * 64 + o], mu);
        mu4[j] = mu;
      }
      *(f32x4*)&mu_out[row * 64 + 4 * b] = mu4;
      f32x4 p4 = {-gamma_f * mu4.x, -gamma_f * mu4.y, -gamma_f * mu4.z, -gamma_f * mu4.w};
      *(f32x4*)&p_lds[tid * 64 + 4 * b] = p4;
    }
  }

  __syncthreads();

  const float step = s_step;
  const f32x2 ns2 = {-step, -step};
  const f32x2 zero2 = {0.f, 0.f};
  const f32x2 one2 = {1.f, 1.f};

  // ---- P^T in C-layout, paired along reg i
  f32x2 pf2[8];
#pragma unroll
  for (int t = 0; t < 4; ++t) {
    float p0 = p_lds[(wv * 16 + 4 * q + 0) * 64 + 16 * t + r16];
    float p1 = p_lds[(wv * 16 + 4 * q + 1) * 64 + 16 * t + r16];
    float p2 = p_lds[(wv * 16 + 4 * q + 2) * 64 + 16 * t + r16];
    float p3 = p_lds[(wv * 16 + 4 * q + 3) * 64 + 16 * t + r16];
    pf2[2 * t] = (f32x2){p0, p1};
    pf2[2 * t + 1] = (f32x2){p2, p3};
  }

  // ---- y LDS pointers
  float* const ywr = &y_lds[wv][4 * q * YSTRIDE + r16];
  const float* const yrd = &y_lds[wv][r16 * YSTRIDE + 8 * q];

  // ---- state (C-layout, f32x2 pairs along reg index i)
  f32x2 yc2[8], wc2[8];
#pragma unroll
  for (int i = 0; i < 8; ++i) {
    yc2[i] = (f32x2){1.0f / 64.0f, 1.0f / 64.0f};
    wc2[i] = yc2[i];
  }
  f32x2 th01 = zero2, th23 = zero2;    // theta per reg-row
  f32x2 thp01 = zero2, thp23 = zero2;  // previous (for extrapolation)
  f32x2 inv01 = {1.f / 64.f, 1.f / 64.f}, inv23 = {1.f / 64.f, 1.f / 64.f};
  int enc_prev = 0x40404040;
  float t_m = 1.0f;

  // initial y -> LDS
#pragma unroll
  for (int t = 0; t < 4; ++t) {
    ywr[0 * YSTRIDE + 16 * t] = yc2[2 * t].x;
    ywr[1 * YSTRIDE + 16 * t] = yc2[2 * t].y;
    ywr[2 * YSTRIDE + 16 * t] = yc2[2 * t + 1].x;
    ywr[3 * YSTRIDE + 16 * t] = yc2[2 * t + 1].y;
  }
  __asm__ __volatile__("" ::: "memory");

#pragma unroll 1
  for (int it = 0; it < N_FISTA; ++it) {
    // ---- 1. A-frags (y bf16-hi only)
    f32x4 r0 = *(const f32x4*)(yrd);
    f32x4 r1 = *(const f32x4*)(yrd + 4);
    f32x4 r2 = *(const f32x4*)(yrd + 32);
    f32x4 r3 = *(const f32x4*)(yrd + 36);
    __asm__ __volatile__("" ::: "memory");
    s16x8 a_h0 = pack_hi(r0, r1);
    s16x8 a_h1 = pack_hi(r2, r3);

    // ---- 2. G^T tiles + v = y - step*g
    f32x2 vc2[8];
#pragma unroll
    for (int t = 0; t < 4; ++t) {
      f32x4 acc{pf2[2 * t].x, pf2[2 * t].y, pf2[2 * t + 1].x, pf2[2 * t + 1].y};
      acc = __builtin_amdgcn_mfma_f32_16x16x32_bf16(a_h0, b_hi[t * 2 + 0], acc, 0, 0, 0);
      acc = __builtin_amdgcn_mfma_f32_16x16x32_bf16(a_h1, b_hi[t * 2 + 1], acc, 0, 0, 0);
      acc = __builtin_amdgcn_mfma_f32_16x16x32_bf16(a_h0, b_lo[t * 2 + 0], acc, 0, 0, 0);
      acc = __builtin_amdgcn_mfma_f32_16x16x32_bf16(a_h1, b_lo[t * 2 + 1], acc, 0, 0, 0);
      vc2[2 * t] = fma2(ns2, (f32x2){acc.x, acc.y}, yc2[2 * t]);
      vc2[2 * t + 1] = fma2(ns2, (f32x2){acc.z, acc.w}, yc2[2 * t + 1]);
    }

    // ---- 3. projection theta: cheap f-only pass, fallback exact loop
    {
      f32x2 F01 = zero2, F23 = zero2;
#pragma unroll
      for (int t = 0; t < 4; ++t) {
        F01 += max2(vc2[2 * t] - th01, zero2);
        F23 += max2(vc2[2 * t + 1] - th23, zero2);
      }
      float f0 = F01.x, f1 = F01.y, f2 = F23.x, f3 = F23.y;
      red4<1>(f0, f1, f2, f3);
      red4<2>(f0, f1, f2, f3);
      red4<4>(f0, f1, f2, f3);
      red4<8>(f0, f1, f2, f3);
      float e = fmaxf(fmaxf(fabsf(f0 - 1.f), fabsf(f1 - 1.f)),
                      fmaxf(fabsf(f2 - 1.f), fabsf(f3 - 1.f)));
      if (__ballot(e > 1e-5f) != 0ull) {
        // carried-slope update, then exact Michelot/Newton
        th01 += (f32x2){(f0 - 1.f) * inv01.x, (f1 - 1.f) * inv01.y};
        th23 += (f32x2){(f2 - 1.f) * inv23.x, (f3 - 1.f) * inv23.y};
#pragma unroll 1
        for (int mm = 0; mm < 16; ++mm) {
          f32x2 G01 = zero2, G23 = zero2;
          int enc = 0x04040404;
#pragma unroll
          for (int t = 0; t < 4; ++t) {
            f32x2 d01 = vc2[2 * t] - th01;
            f32x2 d23 = vc2[2 * t + 1] - th23;
            G01 += max2(d01, zero2);
            G23 += max2(d23, zero2);
            enc += (__float_as_int(d01.x) >> 31);
            enc += (__float_as_int(d01.y) >> 31) << 8;
            enc += (__float_as_int(d23.x) >> 31) << 16;
            enc += (__float_as_int(d23.y) >> 31) << 24;
          }
          float g0 = G01.x, g1 = G01.y, g2 = G23.x, g3 = G23.y;
          red5<1>(g0, g1, g2, g3, enc);
          red5<2>(g0, g1, g2, g3, enc);
          red5<4>(g0, g1, g2, g3, enc);
          red5<8>(g0, g1, g2, g3, enc);
          int n0 = enc & 0xFF, n1 = (enc >> 8) & 0xFF, n2 = (enc >> 16) & 0xFF,
              n3 = (enc >> 24) & 0xFF;
          float i0 = __builtin_amdgcn_rcpf((float)(n0 > 1 ? n0 : 1));
          float i1 = __builtin_amdgcn_rcpf((float)(n1 > 1 ? n1 : 1));
          float i2 = __builtin_amdgcn_rcpf((float)(n2 > 1 ? n2 : 1));
          float i3 = __builtin_amdgcn_rcpf((float)(n3 > 1 ? n3 : 1));
          inv01 = (f32x2){i0, i1};
          inv23 = (f32x2){i2, i3};
          th01 += (f32x2){(g0 - 1.f) * i0, (g1 - 1.f) * i1};
          th23 += (f32x2){(g2 - 1.f) * i2, (g3 - 1.f) * i3};
          bool changed = (enc != enc_prev);
          enc_prev = enc;
          if (__ballot(changed) == 0ull) break;
        }
      }
    }

    // ---- 4. project + momentum + y->LDS + theta extrapolation
    float tn = 0.5f * (1.0f + sqrtf(fmaf(4.0f * t_m, t_m, 1.0f)));
    float c = (t_m - 1.0f) * __builtin_amdgcn_rcpf(tn);
    f32x2 c2 = {c, c};
#pragma unroll
    for (int t = 0; t < 4; ++t) {
      f32x2 wn01 = max2(vc2[2 * t] - th01, zero2);
      f32x2 wn23 = max2(vc2[2 * t + 1] - th23, zero2);
      yc2[2 * t] = fma2(c2, wn01 - wc2[2 * t], wn01);
      yc2[2 * t + 1] = fma2(c2, wn23 - wc2[2 * t + 1], wn23);
      wc2[2 * t] = wn01;
      wc2[2 * t + 1] = wn23;
      ywr[0 * YSTRIDE + 16 * t] = yc2[2 * t].x;
      ywr[1 * YSTRIDE + 16 * t] = yc2[2 * t].y;
      ywr[2 * YSTRIDE + 16 * t] = yc2[2 * t + 1].x;
      ywr[3 * YSTRIDE + 16 * t] = yc2[2 * t + 1].y;
    }
    t_m = tn;
    // theta extrapolation (warm start for next iter's projection)
    f32x2 sv01 = th01, sv23 = th23;
    th01 = fma2(c2, th01 - thp01, th01);
    th23 = fma2(c2, th23 - thp23, th23);
    thp01 = sv01;
    thp23 = sv23;
    __asm__ __volatile__("" ::: "memory");
  }

  // ---- store w (C-layout scatter; wc2 holds converged w)
#pragma unroll
  for (int t = 0; t < 4; ++t) {
    w_out[(rowbase + 4 * q + 0) * 64 + 16 * t + r16] = wc2[2 * t].x;
    w_out[(rowbase + 4 * q + 1) * 64 + 16 * t + r16] = wc2[2 * t].y;
    w_out[(rowbase + 4 * q + 2) * 64 + 16 * t + r16] = wc2[2 * t + 1].x;
    w_out[(rowbase + 4 * q + 3) * 64 + 16 * t + r16] = wc2[2 * t + 1].y;
  }
}

extern "C" void kernel_launch(void* const* d_in, const int* in_sizes, int n_in,
                              void* d_out, int out_size, void* d_ws, size_t ws_size,
                              hipStream_t stream) {
  const float* x = (const float*)d_in[0];
  const float* W1 = (const float*)d_in[1];
  const float* b1 = (const float*)d_in[2];
  const float* W2 = (const float*)d_in[3];
  const float* b2 = (const float*)d_in[4];
  const float* W3 = (const float*)d_in[5];
  const float* b3 = (const float*)d_in[6];
  const float* sigma = (const float*)d_in[7];
  const float* gamma = (const float*)d_in[8];

  float* out = (float*)d_out;
  float* w_out = out;                         // [B, 64] weights
  float* mu_out = out + (size_t)B_ROWS * NA;  // [B, 64] mu

  fused_kernel<<<B_ROWS / 64, 256, 0, stream>>>(x, W1, b1, W2, b2, W3, b3,
                                                sigma, gamma, w_out, mu_out);
}